// Round 1
// baseline (5009.904 us; speedup 1.0000x reference)
//
#include <hip/hip_runtime.h>

#define PAD_IDX 0

typedef __attribute__((ext_vector_type(8))) short short8;
typedef __attribute__((ext_vector_type(4))) float f32x4;

// ---------- helpers ----------
__device__ __forceinline__ unsigned short f32_to_bf16_rne(float f) {
  unsigned int u = __builtin_bit_cast(unsigned int, f);
  u += 0x7FFFu + ((u >> 16) & 1u);
  return (unsigned short)(u >> 16);
}

__device__ __forceinline__ void load16_to_lds(const void* g, void* lds) {
  __builtin_amdgcn_global_load_lds(
      (const __attribute__((address_space(1))) unsigned int*)g,
      (__attribute__((address_space(3))) unsigned int*)lds,
      16, 0, 0);
}

// ---------- kernel 0: sentinel (only if ws too small) ----------
__global__ void sentinel_kernel(float* out) { out[0] = 1.0e6f; }

// ---------- kernel 1: lm_W f32 -> bf16 ----------
__global__ __launch_bounds__(256) void cvt_kernel(const float* __restrict__ in,
                                                  unsigned short* __restrict__ out,
                                                  int n8) {
  int stride = gridDim.x * blockDim.x;
  for (int i = blockIdx.x * blockDim.x + threadIdx.x; i < n8; i += stride) {
    float4 a = ((const float4*)in)[2 * i];
    float4 b = ((const float4*)in)[2 * i + 1];
    ushort4 lo, hi;
    lo.x = f32_to_bf16_rne(a.x); lo.y = f32_to_bf16_rne(a.y);
    lo.z = f32_to_bf16_rne(a.z); lo.w = f32_to_bf16_rne(a.w);
    hi.x = f32_to_bf16_rne(b.x); hi.y = f32_to_bf16_rne(b.y);
    hi.z = f32_to_bf16_rne(b.z); hi.w = f32_to_bf16_rne(b.w);
    ((ushort4*)out)[2 * i] = lo;
    ((ushort4*)out)[2 * i + 1] = hi;
  }
}

// ---------- kernel 2: xw[r][j] = emb[tok[r]] . Wx[j] + bias[j]  (f32) ----------
// M=4096 (r), N=1024 (j), K=512. Tiles 64x64, BK=32. Grid 64*16=1024 WGs, 256 thr.
__global__ __launch_bounds__(256) void xw_kernel(const int* __restrict__ tok,
                                                 const float* __restrict__ emb,
                                                 const float* __restrict__ Wx,
                                                 const float* __restrict__ bias,
                                                 float* __restrict__ xw) {
  __shared__ float At[32][68];  // [k][m], padded
  __shared__ float Bt[32][68];  // [k][n]
  __shared__ int stok[64];
  int tid = threadIdx.x;
  int tm = blockIdx.x & 63;   // 4096/64
  int tn = blockIdx.x >> 6;   // 1024/64
  int r0 = tm * 64, j0 = tn * 64;
  if (tid < 64) stok[tid] = tok[r0 + tid];
  int tx = tid & 15, ty = tid >> 4;
  float acc[4][4] = {};
  for (int kt = 0; kt < 512; kt += 32) {
    __syncthreads();
    #pragma unroll
    for (int ii = 0; ii < 2; ++ii) {
      int idx = tid * 2 + ii;      // 0..511
      int m = idx >> 3, fv = idx & 7;
      float4 va = *(const float4*)&emb[(size_t)stok[m] * 512 + kt + fv * 4];
      float4 vb = *(const float4*)&Wx[(size_t)(j0 + m) * 512 + kt + fv * 4];
      At[fv * 4 + 0][m] = va.x; At[fv * 4 + 1][m] = va.y;
      At[fv * 4 + 2][m] = va.z; At[fv * 4 + 3][m] = va.w;
      Bt[fv * 4 + 0][m] = vb.x; Bt[fv * 4 + 1][m] = vb.y;
      Bt[fv * 4 + 2][m] = vb.z; Bt[fv * 4 + 3][m] = vb.w;
    }
    __syncthreads();
    #pragma unroll
    for (int k = 0; k < 32; ++k) {
      float4 a4 = *(const float4*)&At[k][ty * 4];
      float4 b4 = *(const float4*)&Bt[k][tx * 4];
      float av[4] = {a4.x, a4.y, a4.z, a4.w};
      float bv[4] = {b4.x, b4.y, b4.z, b4.w};
      #pragma unroll
      for (int i = 0; i < 4; ++i)
        #pragma unroll
        for (int jj = 0; jj < 4; ++jj) acc[i][jj] = fmaf(av[i], bv[jj], acc[i][jj]);
    }
  }
  #pragma unroll
  for (int i = 0; i < 4; ++i) {
    size_t row = (size_t)(r0 + ty * 4 + i) * 1024 + j0 + tx * 4;
    #pragma unroll
    for (int jj = 0; jj < 4; ++jj)
      xw[row + jj] = acc[i][jj] + bias[j0 + tx * 4 + jj];
  }
}

// ---------- kernel 3: recurrence ----------
// 256 WGs x 256 thr, 1 WG/CU. Chain b = blk>>4 (16 WGs per chain, 64 j-rows each).
// Thread (jj,kk): j = g*64+jj, k-slices {16*i + 4*kk + c}. Wh row slice in 256 VGPRs.
// h exchange via device-scope atomics + per-chain monotonic barrier counter.
__global__ __launch_bounds__(256, 1) void rec_kernel(const float* __restrict__ Wh,
                                                     const float* __restrict__ xw,
                                                     const int* __restrict__ tok,
                                                     float* hbuf,            // [2][16][1024]
                                                     unsigned short* __restrict__ h_all,
                                                     unsigned int* bar) {    // [16]
  int b = blockIdx.x >> 4;
  int g = blockIdx.x & 15;
  int tid = threadIdx.x;
  int jj = tid >> 2, kk = tid & 3;
  int j = g * 64 + jj;
  float4 W[64];
  {
    const float* base = Wh + (size_t)j * 1024 + kk * 4;
    #pragma unroll
    for (int i = 0; i < 64; ++i) W[i] = *(const float4*)(base + i * 16);
  }
  __shared__ float hs[1024];
  float* h0 = hbuf + b * 1024;
  float* h1 = hbuf + 16 * 1024 + b * 1024;
  for (int t = 0; t < 256; ++t) {
    if (t > 0) {
      if (tid == 0) {
        unsigned int target = (unsigned int)(16 * t);
        long guard = 0;
        while (__hip_atomic_load(bar + b, __ATOMIC_ACQUIRE, __HIP_MEMORY_SCOPE_AGENT) < target) {
          __builtin_amdgcn_s_sleep(1);
          if (++guard > (1L << 30)) break;  // safety against pathological stall
        }
      }
      __syncthreads();
    }
    const float* hin = (t & 1) ? h1 : h0;
    float* hout = (t & 1) ? h0 : h1;
    #pragma unroll
    for (int i = 0; i < 4; ++i) {
      int idx = tid + i * 256;
      hs[idx] = __hip_atomic_load(hin + idx, __ATOMIC_RELAXED, __HIP_MEMORY_SCOPE_AGENT);
    }
    __syncthreads();
    float a0 = 0.f, a1 = 0.f, a2 = 0.f, a3 = 0.f;
    const float* hk = hs + kk * 4;
    #pragma unroll
    for (int i = 0; i < 64; ++i) {
      float4 w = W[i];
      float4 h4 = *(const float4*)(hk + i * 16);
      a0 = fmaf(w.x, h4.x, a0);
      a1 = fmaf(w.y, h4.y, a1);
      a2 = fmaf(w.z, h4.z, a2);
      a3 = fmaf(w.w, h4.w, a3);
    }
    float acc = (a0 + a1) + (a2 + a3);
    acc += __shfl_xor(acc, 1);
    acc += __shfl_xor(acc, 2);
    if (kk == 0) {
      int tkn = tok[b * 256 + t];
      float pre = xw[(size_t)(b * 256 + t) * 1024 + j] + acc;
      float hnew = (tkn != PAD_IDX) ? tanhf(pre) : hs[j];
      __hip_atomic_store(hout + j, hnew, __ATOMIC_RELAXED, __HIP_MEMORY_SCOPE_AGENT);
      h_all[(size_t)(b * 256 + t) * 1024 + j] = f32_to_bf16_rne(hnew);
    }
    __syncthreads();  // drains vmcnt(0): all stores coherent-complete before arrive
    if (tid == 0)
      __hip_atomic_fetch_add(bar + b, 1u, __ATOMIC_RELEASE, __HIP_MEMORY_SCOPE_AGENT);
  }
}

// ---------- kernel 4: logits = h_all(bf16) @ lm_W(bf16)^T, f32 out ----------
// M=4096, N=32000, K=1024. 128x128 tile, BK=64, 4 waves (2x2), 16x16x32 MFMA.
// global_load_lds(16B) staging with pre-swizzled source (XOR granule swizzle).
__global__ __launch_bounds__(256) void gemm_kernel(const unsigned short* __restrict__ A,
                                                   const unsigned short* __restrict__ B,
                                                   float* __restrict__ C) {
  __shared__ unsigned short sA[128 * 64];
  __shared__ unsigned short sB[128 * 64];
  int tid = threadIdx.x;
  int lane = tid & 63, wave = tid >> 6;
  int id = blockIdx.x;
  int s = (id & 7) * 1000 + (id >> 3);  // bijective XCD swizzle (8000 % 8 == 0)
  int tm = s & 31, tn = s >> 5;         // tm fast -> consecutive blocks share B panel
  int r0 = tm * 128, c0 = tn * 128;
  int wm = wave >> 1, wn = wave & 1;
  f32x4 zero = {0.f, 0.f, 0.f, 0.f};
  f32x4 acc[4][4];
  #pragma unroll
  for (int i = 0; i < 4; ++i)
    #pragma unroll
    for (int jx = 0; jx < 4; ++jx) acc[i][jx] = zero;

  for (int kt = 0; kt < 16; ++kt) {
    __syncthreads();
    #pragma unroll
    for (int i = 0; i < 4; ++i) {
      int slot = i * 256 + tid;        // 0..1023
      int m = slot >> 3, sg = slot & 7;
      int kg = sg ^ (m & 7);           // inverse-swizzled source granule
      const unsigned short* ga = A + (size_t)(r0 + m) * 1024 + kt * 64 + kg * 8;
      load16_to_lds(ga, &sA[(i * 256 + wave * 64) * 8]);
      const unsigned short* gb = B + (size_t)(c0 + m) * 1024 + kt * 64 + kg * 8;
      load16_to_lds(gb, &sB[(i * 256 + wave * 64) * 8]);
    }
    __syncthreads();
    #pragma unroll
    for (int kkb = 0; kkb < 2; ++kkb) {
      short8 af[4], bf[4];
      int kbyte = kkb * 64 + (lane >> 4) * 16;
      #pragma unroll
      for (int i = 0; i < 4; ++i) {
        int row = wm * 64 + i * 16 + (lane & 15);
        int off = row * 128 + (kbyte ^ ((row & 7) << 4));
        af[i] = *(const short8*)((const char*)sA + off);
        int rowb = wn * 64 + i * 16 + (lane & 15);
        int offb = rowb * 128 + (kbyte ^ ((rowb & 7) << 4));
        bf[i] = *(const short8*)((const char*)sB + offb);
      }
      #pragma unroll
      for (int i = 0; i < 4; ++i)
        #pragma unroll
        for (int jx = 0; jx < 4; ++jx)
          acc[i][jx] = __builtin_amdgcn_mfma_f32_16x16x32_bf16(af[i], bf[jx], acc[i][jx], 0, 0, 0);
    }
  }
  int rbase = r0 + wm * 64 + (lane >> 4) * 4;
  int cbase = c0 + wn * 64 + (lane & 15);
  #pragma unroll
  for (int i = 0; i < 4; ++i)
    #pragma unroll
    for (int jx = 0; jx < 4; ++jx)
      #pragma unroll
      for (int q = 0; q < 4; ++q)
        C[(size_t)(rbase + i * 16 + q) * 32000 + cbase + jx * 16] = acc[i][jx][q];
}

// ---------- launch ----------
extern "C" void kernel_launch(void* const* d_in, const int* in_sizes, int n_in,
                              void* d_out, int out_size, void* d_ws, size_t ws_size,
                              hipStream_t stream) {
  const int* tok = (const int*)d_in[0];
  const float* emb = (const float*)d_in[1];
  const float* Wx = (const float*)d_in[2];
  const float* Wh = (const float*)d_in[3];
  const float* bias = (const float*)d_in[4];
  const float* lmW = (const float*)d_in[5];
  float* out = (float*)d_out;

  // ws layout (bytes):
  const size_t OFF_LMW = 0;                       // bf16 lm_W: 65,536,000
  const size_t OFF_XW = 65536000;                 // f32 xw:   16,777,216
  const size_t OFF_HALL = OFF_XW + 16777216;      // bf16 h_all: 8,388,608
  const size_t OFF_HBUF = OFF_HALL + 8388608;     // f32 hbuf: 131,072
  const size_t OFF_BAR = OFF_HBUF + 131072;       // u32 bar: 64
  const size_t NEED = OFF_BAR + 64;
  if (ws_size < NEED) {  // signal: absmax ~1e6 means "workspace too small"
    sentinel_kernel<<<1, 1, 0, stream>>>(out);
    return;
  }
  char* ws = (char*)d_ws;
  unsigned short* lmW_bf = (unsigned short*)(ws + OFF_LMW);
  float* xw = (float*)(ws + OFF_XW);
  unsigned short* h_all = (unsigned short*)(ws + OFF_HALL);
  float* hbuf = (float*)(ws + OFF_HBUF);
  unsigned int* bar = (unsigned int*)(ws + OFF_BAR);

  hipMemsetAsync(ws + OFF_HBUF, 0, 131072 + 64, stream);  // h0 = 0, barriers = 0
  cvt_kernel<<<2048, 256, 0, stream>>>(lmW, lmW_bf, 32000 * 1024 / 8);
  xw_kernel<<<1024, 256, 0, stream>>>(tok, emb, Wx, bias, xw);
  rec_kernel<<<256, 256, 0, stream>>>(Wh, xw, tok, hbuf, h_all, bar);
  gemm_kernel<<<8000, 256, 0, stream>>>(h_all, lmW_bf, out);
}